// Round 1
// baseline (8452.320 us; speedup 1.0000x reference)
//
#include <hip/hip_runtime.h>
#include <math.h>

// ---------------- problem constants ----------------
namespace {
constexpr int NB = 4;       // batch
constexpr int SEQ = 128;    // total_len = TH + steps
constexpr int TH_ = 120;    // history length
constexpr int NSTEP = 8;
constexpr int DMODEL = 512;
constexpr int NHEAD = 8;
constexpr int DHEAD = 64;
constexpr int DFFN = 2048;
constexpr int DIN = 32;
constexpr int BKK = 32;     // GEMM K-chunk
constexpr float SCALE_EMB = 22.627416997969522f; // sqrt(512)
constexpr float LN_EPS = 1e-5f;
constexpr float NEGF = -3.4028234663852886e38f;  // jnp.finfo(f32).min
constexpr float PE_C = -0.017988946039015984f;   // -ln(10000)/512
}

// ---------------- device helpers ----------------
__device__ __forceinline__ float wave_sum(float v){
#pragma unroll
  for(int off=32;off;off>>=1) v += __shfl_xor(v,off,64);
  return v;
}
__device__ __forceinline__ float blk_sum(float v, float* scr){
  v = wave_sum(v);
  __syncthreads();
  if((threadIdx.x&63)==0) scr[threadIdx.x>>6]=v;
  __syncthreads();
  return scr[0]+scr[1]+scr[2]+scr[3];
}
__device__ __forceinline__ float gelu_t(float x){
  // jax.nn.gelu default (approximate=True, tanh form)
  float t = 0.7978845608028654f*(x + 0.044715f*x*x*x);
  return 0.5f*x*(1.0f + tanhf(t));
}
__device__ __forceinline__ float pe_val(int t, int d){
  float div = expf((float)(d & ~1) * PE_C);
  float a = (float)t * div;
  return (d & 1) ? cosf(a) : sinf(a);
}

// ---------------- h0 init: embed history (+zeros suffix) + positional enc ----------------
__global__ __launch_bounds__(256) void init_h0(const float* __restrict__ hist,
                                               const float* __restrict__ W_emb,
                                               const float* __restrict__ b_emb,
                                               float* __restrict__ h0){
  int bt = blockIdx.x;            // b*SEQ + t
  int b = bt >> 7, t = bt & 127;
  __shared__ float x[DIN];
  if(threadIdx.x < DIN)
    x[threadIdx.x] = (t < TH_) ? hist[((size_t)b*TH_ + t)*DIN + threadIdx.x] : 0.f;
  __syncthreads();
  for(int d = threadIdx.x; d < DMODEL; d += 256){
    float s = 0.f;
#pragma unroll 8
    for(int i=0;i<DIN;i++) s += W_emb[d*DIN+i]*x[i];
    h0[(size_t)bt*DMODEL + d] = SCALE_EMB*(s + b_emb[d]) + pe_val(t,d);
  }
}

// ---------------- M1 = scale*Wr1a@W_emb, cb1 = br1 + scale*Wr1a@b_emb, cur_x init ---------
__global__ __launch_bounds__(256) void init_misc(const float* __restrict__ Wr1,
                                                 const float* __restrict__ W_emb,
                                                 const float* __restrict__ b_emb,
                                                 const float* __restrict__ br1,
                                                 const float* __restrict__ hist,
                                                 float* __restrict__ M1,
                                                 float* __restrict__ cb1,
                                                 float* __restrict__ cur_x){
  __shared__ float row[DMODEL];
  int j0 = blockIdx.x*8;
  for(int jj=0;jj<8;jj++){
    int j = j0+jj;
    for(int k=threadIdx.x;k<DMODEL;k+=256) row[k] = Wr1[(size_t)j*1024 + k];
    __syncthreads();
    if(threadIdx.x < DIN){
      int i = threadIdx.x; float s = 0.f;
      for(int k=0;k<DMODEL;k++) s += row[k]*W_emb[k*DIN+i];
      M1[j*DIN+i] = SCALE_EMB*s;
    } else if(threadIdx.x == DIN){
      float s=0.f;
      for(int k=0;k<DMODEL;k++) s += row[k]*b_emb[k];
      cb1[j] = br1[j] + SCALE_EMB*s;
    }
    __syncthreads();
  }
  if(blockIdx.x==0 && threadIdx.x<NB*DIN){
    int b = threadIdx.x>>5, i = threadIdx.x&31;
    cur_x[b*DIN+i] = hist[((size_t)b*TH_ + (TH_-1))*DIN + i];
  }
}

// ---------------- tiled GEMM stage: C = act(LN?(A)@W^T + bias + resid) -------------------
// tile 32 rows x 64 cols, 256 threads, 2x4 per thread.
__global__ __launch_bounds__(256) void gemm_stage(
    const float* __restrict__ A, int a_rs,
    const float* __restrict__ lng, const float* __restrict__ lnb,
    float* __restrict__ Ast,
    const float* __restrict__ W, const float* __restrict__ bias,
    const float* __restrict__ resid,
    float* __restrict__ C, int c_rs, int c_mode,
    int K, int t_lo, int t_cnt, int act)
{
  int b = blockIdx.z;
  int n0 = blockIdx.x*64;
  int m0 = blockIdx.y*32;
  int tid = threadIdx.x;
  __shared__ float a_s[BKK][34];
  __shared__ float w_s[BKK][68];
  __shared__ float mu_s[32], rs_s[32];
  int tmax = t_lo + t_cnt;

  if(lng){
    int wv = tid>>6, ln = tid&63;
    for(int r=wv;r<32;r+=4){
      int t = t_lo + m0 + r;
      float mu = 0.f, rs = 1.f;
      if(t < tmax){
        const float* ap = A + (size_t)(b*SEQ+t)*a_rs;
        float s = 0.f;
        for(int k=ln;k<K;k+=64) s += ap[k];
        s = wave_sum(s);
        mu = s/(float)K;
        float v = 0.f;
        for(int k=ln;k<K;k+=64){ float d0 = ap[k]-mu; v += d0*d0; }
        v = wave_sum(v);
        rs = rsqrtf(v/(float)K + LN_EPS);
      }
      if(ln==0){ mu_s[r]=mu; rs_s[r]=rs; }
    }
    __syncthreads();
  }

  float acc[2][4] = {};
  int tr = (tid>>4)*2;
  int tc = (tid&15)*4;

  for(int k0=0;k0<K;k0+=BKK){
    { // stage A chunk (optionally layernormed)
      int r = tid>>3, kq = (tid&7)*4;
      int t = t_lo + m0 + r;
      float4 v = make_float4(0.f,0.f,0.f,0.f);
      if(t < tmax){
        const float* ap = A + (size_t)(b*SEQ+t)*a_rs + (k0+kq);
        v = *(const float4*)ap;
        if(lng){
          float mu = mu_s[r], rs = rs_s[r];
          int k = k0+kq;
          v.x = (v.x-mu)*rs*lng[k+0] + lnb[k+0];
          v.y = (v.y-mu)*rs*lng[k+1] + lnb[k+1];
          v.z = (v.z-mu)*rs*lng[k+2] + lnb[k+2];
          v.w = (v.w-mu)*rs*lng[k+3] + lnb[k+3];
          if(Ast && blockIdx.x==0)
            *(float4*)(Ast + (size_t)(b*SEQ+t)*DMODEL + k) = v;
        }
      }
      a_s[kq+0][r]=v.x; a_s[kq+1][r]=v.y; a_s[kq+2][r]=v.z; a_s[kq+3][r]=v.w;
    }
    { // stage W chunk
      int nn = tid>>3, kq = (tid&7)*4;
#pragma unroll
      for(int h2=0;h2<2;h2++){
        int n = nn + h2*32;
        const float* wp = W + (size_t)(n0+n)*K + (k0+kq);
        float4 v = *(const float4*)wp;
        w_s[kq+0][n]=v.x; w_s[kq+1][n]=v.y; w_s[kq+2][n]=v.z; w_s[kq+3][n]=v.w;
      }
    }
    __syncthreads();
#pragma unroll
    for(int kk=0;kk<BKK;kk++){
      float2 av = *(const float2*)&a_s[kk][tr];
      float4 wv = *(const float4*)&w_s[kk][tc];
      acc[0][0]+=av.x*wv.x; acc[0][1]+=av.x*wv.y; acc[0][2]+=av.x*wv.z; acc[0][3]+=av.x*wv.w;
      acc[1][0]+=av.y*wv.x; acc[1][1]+=av.y*wv.y; acc[1][2]+=av.y*wv.z; acc[1][3]+=av.y*wv.w;
    }
    __syncthreads();
  }

#pragma unroll
  for(int i=0;i<2;i++){
    int t = t_lo + m0 + tr + i;
    if(t >= tmax) continue;
#pragma unroll
    for(int j=0;j<4;j++){
      int n = n0 + tc + j;
      float v = acc[i][j];
      if(bias)  v += bias[n];
      if(resid) v += resid[(size_t)(b*SEQ+t)*DMODEL + n];
      if(act==1) v = gelu_t(v);
      if(c_mode==0) C[(size_t)(b*SEQ+t)*c_rs + n] = v;
      else          C[((size_t)(b*NHEAD + (n>>6))*SEQ + t)*DHEAD + (n&63)] = v;
    }
  }
}

// ---------------- small-row GEMM (<=9 rows/batch), K-parallel across 16 lanes -------------
__global__ __launch_bounds__(256) void gemm_rows(
    const float* __restrict__ A, int a_rs,
    const float* __restrict__ lng, const float* __restrict__ lnb,
    float* __restrict__ Ast,
    const float* __restrict__ W, const float* __restrict__ bias,
    const float* __restrict__ resid,
    float* __restrict__ C, int c_rs, int c_mode,
    int K, int t_lo, int t_cnt, int act)
{
  int b = blockIdx.y;
  int c0 = blockIdx.x*16;
  int tid = threadIdx.x;
  int kl = tid&15, cg = tid>>4;
  __shared__ float al[9][520];
  __shared__ float scr[4];
  int nr = t_cnt;  // <= 9 by construction

  if(lng){ // K == DMODEL here
    for(int r=0;r<nr;r++){
      const float* ap = A + (size_t)(b*SEQ + t_lo + r)*a_rs;
      float s = 0.f;
      for(int k=tid;k<K;k+=256) s += ap[k];
      s = blk_sum(s, scr);
      float mu = s/(float)K;
      float v = 0.f;
      for(int k=tid;k<K;k+=256){ float d0 = ap[k]-mu; v += d0*d0; }
      v = blk_sum(v, scr);
      float rs = rsqrtf(v/(float)K + LN_EPS);
      for(int k=tid;k<K;k+=256){
        float x = (ap[k]-mu)*rs*lng[k] + lnb[k];
        al[r][k] = x;
        if(Ast && blockIdx.x==0) Ast[(size_t)(b*SEQ+t_lo+r)*DMODEL + k] = x;
      }
    }
    __syncthreads();
  }

  float acc[9];
#pragma unroll
  for(int r=0;r<9;r++) acc[r]=0.f;
  const float* wp = W + (size_t)(c0+cg)*K;
  if(lng){
    for(int k=kl;k<K;k+=16){
      float w0 = wp[k];
      for(int r=0;r<nr;r++) acc[r] += al[r][k]*w0;
    }
  } else {
    for(int k=kl;k<K;k+=16){
      float w0 = wp[k];
      for(int r=0;r<nr;r++) acc[r] += A[(size_t)(b*SEQ+t_lo+r)*a_rs + k]*w0;
    }
  }
#pragma unroll
  for(int off=1;off<16;off<<=1)
    for(int r=0;r<9;r++) acc[r] += __shfl_xor(acc[r],off,64);
  if(kl==0){
    int n = c0+cg;
    for(int r=0;r<nr;r++){
      float v = acc[r];
      if(bias)  v += bias[n];
      if(resid) v += resid[(size_t)(b*SEQ+t_lo+r)*DMODEL + n];
      if(act==1) v = gelu_t(v);
      int t = t_lo + r;
      if(c_mode==0) C[(size_t)(b*SEQ+t)*c_rs + n] = v;
      else          C[((size_t)(b*NHEAD + (n>>6))*SEQ + t)*DHEAD + (n&63)] = v;
    }
  }
}

// ---------------- fused attention per (b,h): anti-causal mask, row-127 -> uniform ---------
__global__ __launch_bounds__(256) void attn_k(const float* __restrict__ qb,
                                              const float* __restrict__ kb,
                                              const float* __restrict__ vb,
                                              float* __restrict__ att,
                                              int t_lo, int t_cnt){
  int b = blockIdx.z, h = blockIdx.y;
  int r0 = blockIdx.x*32;
  int nr = min(32, t_cnt - r0);
  const float* Kh = kb + (size_t)(b*NHEAD+h)*SEQ*DHEAD;
  const float* Vh = vb + (size_t)(b*NHEAD+h)*SEQ*DHEAD;
  const float* Qh = qb + (size_t)(b*NHEAD+h)*SEQ*DHEAD;
  __shared__ float kv[SEQ][DHEAD];    // K (swizzled) then V (plain)
  __shared__ float wsm[32][132];
  __shared__ float qs[32][DHEAD];
  int tid = threadIdx.x;
  int d = tid&63, rr = tid>>6;

  for(int k=rr;k<SEQ;k+=4) kv[k][d ^ (k&60)] = Kh[k*DHEAD + d];
  for(int r=rr;r<nr;r+=4)  qs[r][d] = Qh[(size_t)(t_lo+r0+r)*DHEAD + d];
  __syncthreads();

  { // logits (masked: keep only k > t; -FLT_MAX elsewhere)
    int k = tid&127, g = tid>>7;
    for(int r=g;r<nr;r+=2){
      int t = t_lo + r0 + r;
      float lg = NEGF;
      if(k > t){
        int sw = k&60;
        float s = 0.f;
#pragma unroll 8
        for(int dd=0;dd<DHEAD;dd++) s += qs[r][dd]*kv[k][dd^sw];
        lg = s*0.125f;   // / sqrt(DHEAD)
      }
      wsm[r][k] = lg;
    }
  }
  __syncthreads();

  { // softmax per row (all-masked row -> exact uniform 1/128, matching jnp)
    int ln = tid&63, wv = tid>>6;
    for(int r=wv;r<nr;r+=4){
      float l0 = wsm[r][ln], l1 = wsm[r][ln+64];
      float m = fmaxf(l0,l1);
#pragma unroll
      for(int off=32;off;off>>=1) m = fmaxf(m, __shfl_xor(m,off,64));
      float e0 = expf(l0-m), e1 = expf(l1-m);
      float s = e0+e1;
      s = wave_sum(s);
      float inv = 1.f/s;
      wsm[r][ln] = e0*inv; wsm[r][ln+64] = e1*inv;
    }
  }
  __syncthreads();

  for(int k=rr;k<SEQ;k+=4) kv[k][d] = Vh[k*DHEAD + d];   // overwrite with V
  __syncthreads();

  { // out = w @ V
    int dq = (tid&15)*4, rg = tid>>4;
    for(int r=rg;r<nr;r+=16){
      float4 acc = make_float4(0.f,0.f,0.f,0.f);
      for(int k=0;k<SEQ;k++){
        float w0 = wsm[r][k];
        float4 v = *(const float4*)&kv[k][dq];
        acc.x += w0*v.x; acc.y += w0*v.y; acc.z += w0*v.z; acc.w += w0*v.w;
      }
      int t = t_lo + r0 + r;
      *(float4*)(att + (size_t)(b*SEQ+t)*DMODEL + h*DHEAD + dq) = acc;
    }
  }
}

// ---------------- ctx = LN2_3(r2[ptr-1]); ctxt = Wr1b@ctx + cb1 --------------------------
__global__ __launch_bounds__(256) void ctx_k(const float* __restrict__ r2,
                                             const float* __restrict__ g2,
                                             const float* __restrict__ b2,
                                             const float* __restrict__ Wr1,
                                             const float* __restrict__ cb1,
                                             float* __restrict__ ctxt, int ptr){
  int b = blockIdx.y; int j0 = blockIdx.x*128;
  __shared__ float raw[DMODEL], ctx[DMODEL], scr[4];
  int tid = threadIdx.x;
  const float* rp = r2 + (size_t)(b*SEQ + ptr-1)*DMODEL;
  for(int k=tid;k<DMODEL;k+=256) raw[k]=rp[k];
  __syncthreads();
  float s = 0.f;
  for(int k=tid;k<DMODEL;k+=256) s += raw[k];
  s = blk_sum(s, scr);
  float mu = s/(float)DMODEL;
  float v = 0.f;
  for(int k=tid;k<DMODEL;k+=256){ float d0 = raw[k]-mu; v += d0*d0; }
  v = blk_sum(v, scr);
  float rs = rsqrtf(v/(float)DMODEL + LN_EPS);
  for(int k=tid;k<DMODEL;k+=256) ctx[k] = (raw[k]-mu)*rs*g2[k] + b2[k];
  __syncthreads();
  int wv = tid>>6, ln = tid&63;
  for(int jj=wv;jj<128;jj+=4){
    int j = j0+jj;
    const float* wp = Wr1 + (size_t)j*1024 + 512;
    float acc = 0.f;
#pragma unroll
    for(int q=0;q<8;q++){ int k = ln + 64*q; acc += wp[k]*ctx[k]; }
    acc = wave_sum(acc);
    if(ln==0) ctxt[b*DFFN + j] = acc + cb1[j];
  }
}

// ---------------- refine substep: g = gelu(M1@cur + ctxt); parts = Wr2_slice@g -----------
__global__ __launch_bounds__(256) void refine_sub(const float* __restrict__ M1,
                                                  const float* __restrict__ ctxt,
                                                  const float* __restrict__ Wr2,
                                                  const float* __restrict__ br2,
                                                  const float* __restrict__ cur_x,
                                                  float* __restrict__ curv,
                                                  float* __restrict__ parts, int sub){
  int b = blockIdx.y, wg = blockIdx.x;
  __shared__ float cur_s[DIN], g_s[512];
  int tid = threadIdx.x;
  if(tid < DIN){
    int i = tid; float c;
    if(sub==0) c = cur_x[b*DIN+i];
    else {
      int pb = (sub-1)&1;
      c = curv[(pb*NB+b)*DIN + i];
      float d = br2[i];
      for(int w=0;w<4;w++) d += parts[((pb*NB+b)*4+w)*DIN + i];
      c += d;
    }
    cur_s[i] = c;
    if(wg==0) curv[((sub&1)*NB+b)*DIN + i] = c;
  }
  __syncthreads();
  int jbase = wg*512;
  for(int jj=tid;jj<512;jj+=256){
    int j = jbase+jj;
    float u = ctxt[b*DFFN + j];
    const float* mp = M1 + (size_t)j*DIN;
#pragma unroll 8
    for(int i=0;i<DIN;i++) u += mp[i]*cur_s[i];
    g_s[jj] = gelu_t(u);
  }
  __syncthreads();
  int wv = tid>>6, ln = tid&63;
  for(int q=0;q<8;q++){
    int i = wv*8 + q;
    float acc = 0.f;
#pragma unroll
    for(int p=0;p<8;p++){ int jj = ln + 64*p; acc += Wr2[(size_t)i*DFFN + jbase + jj]*g_s[jj]; }
    acc = wave_sum(acc);
    if(ln==0) parts[((sub&1)*NB+b)*4*DIN + wg*DIN + i] = acc;
  }
}

// ---------------- finalize step: pred, cur_x, new h0 row ---------------------------------
__global__ __launch_bounds__(256) void finalize_k(const float* __restrict__ curv,
                                                  const float* __restrict__ parts,
                                                  const float* __restrict__ br2,
                                                  const float* __restrict__ W_emb,
                                                  const float* __restrict__ b_emb,
                                                  float* __restrict__ cur_x,
                                                  float* __restrict__ h0,
                                                  float* __restrict__ out,
                                                  int s, int ptr){
  int b = blockIdx.x; int tid = threadIdx.x;
  __shared__ float c5[DIN];
  if(tid < DIN){
    int i = tid;
    float c = curv[(0*NB+b)*DIN + i];      // sub4 wrote buffer 0
    float d = br2[i];
    for(int w=0;w<4;w++) d += parts[((0*NB+b)*4+w)*DIN + i];
    c += d;
    c5[i] = c;
    out[(b*NSTEP + s)*DIN + i] = c;
    cur_x[b*DIN + i] = c;
  }
  __syncthreads();
  for(int d0=tid; d0<DMODEL; d0+=256){
    float s2 = 0.f;
#pragma unroll 8
    for(int i=0;i<DIN;i++) s2 += W_emb[d0*DIN+i]*c5[i];
    h0[(size_t)(b*SEQ + ptr)*DMODEL + d0] = SCALE_EMB*(s2 + b_emb[d0]) + pe_val(ptr, d0);
  }
}

// ---------------- host ----------------
extern "C" void kernel_launch(void* const* d_in, const int* in_sizes, int n_in,
                              void* d_out, int out_size, void* d_ws, size_t ws_size,
                              hipStream_t stream) {
  (void)in_sizes; (void)n_in; (void)out_size; (void)ws_size;
  const float* hist = (const float*)d_in[0];
  const float* W_emb= (const float*)d_in[2];
  const float* b_emb= (const float*)d_in[3];
  const float* Wq   = (const float*)d_in[4];
  const float* Wk   = (const float*)d_in[5];
  const float* Wv   = (const float*)d_in[6];
  const float* Wo   = (const float*)d_in[7];
  const float* ln1g = (const float*)d_in[8];
  const float* ln1b = (const float*)d_in[9];
  const float* W1   = (const float*)d_in[10];
  const float* b1   = (const float*)d_in[11];
  const float* W2   = (const float*)d_in[12];
  const float* b2v  = (const float*)d_in[13];
  const float* ln2g = (const float*)d_in[14];
  const float* ln2b = (const float*)d_in[15];
  const float* Wr1  = (const float*)d_in[16];
  const float* br1  = (const float*)d_in[17];
  const float* Wr2  = (const float*)d_in[18];
  const float* br2  = (const float*)d_in[19];
  float* out = (float*)d_out;
  float* ws  = (float*)d_ws;

  const size_t SZ_BTD = (size_t)NB*SEQ*DMODEL;   // 262144
  float* h0   = ws;               // BTD
  float* r1   = h0   + SZ_BTD;
  float* r2   = r1   + SZ_BTD;
  float* hln  = r2   + SZ_BTD;
  float* hp   = hln  + SZ_BTD;
  float* att  = hp   + SZ_BTD;
  float* qb   = att  + SZ_BTD;    // [b][h][t][64]
  float* kb   = qb   + SZ_BTD;
  float* vb   = kb   + SZ_BTD;
  float* fbuf = vb   + SZ_BTD;    // [b][t][2048]
  float* M1   = fbuf + (size_t)NB*SEQ*DFFN;
  float* cb1  = M1   + (size_t)DFFN*DIN;
  float* ctxt = cb1  + DFFN;
  float* curv = ctxt + (size_t)NB*DFFN;   // 2*NB*32
  float* parts= curv + 2*NB*DIN;          // 2*NB*4*32
  float* cur_x= parts+ 2*NB*4*DIN;

  init_h0<<<dim3(NB*SEQ),dim3(256),0,stream>>>(hist,W_emb,b_emb,h0);
  init_misc<<<dim3(256),dim3(256),0,stream>>>(Wr1,W_emb,b_emb,br1,hist,M1,cb1,cur_x);

  auto gemm = [&](const float* A,int a_rs,const float* g,const float* bb,float* Ast,
                  const float* W,const float* bias,const float* resid,
                  float* C,int c_rs,int c_mode,int N,int K,int lo,int cnt,int act){
    if(cnt > 9){
      dim3 gd(N/64,(cnt+31)/32,NB);
      gemm_stage<<<gd,dim3(256),0,stream>>>(A,a_rs,g,bb,Ast,W,bias,resid,C,c_rs,c_mode,K,lo,cnt,act);
    } else {
      dim3 gd(N/16,NB);
      gemm_rows<<<gd,dim3(256),0,stream>>>(A,a_rs,g,bb,Ast,W,bias,resid,C,c_rs,c_mode,K,lo,cnt,act);
    }
  };

  for(int s=0;s<NSTEP;s++){
    int ptr = TH_ + s;
    for(int l=0;l<4;l++){
      int qlo,qc,klo,kc,vlo,vc,alo,ac,olo,oc;
      if(l<2){ qlo=0;qc=SEQ; klo=0;kc=SEQ; vlo=0;vc=SEQ; alo=0;ac=SEQ; olo=0;oc=SEQ; }
      else if(l==2){
        qlo=ptr-1; qc=SEQ-(ptr-1); klo=ptr; kc=SEQ-ptr; vlo=0; vc=SEQ;
        alo=ptr-1; ac=SEQ-(ptr-1); olo=ptr-1; oc=SEQ-(ptr-1);
      } else {
        qlo=ptr-1; qc=1; klo=ptr; kc=SEQ-ptr; vlo=ptr; vc=SEQ-ptr;
        alo=ptr-1; ac=1; olo=ptr-1; oc=1;
      }
      const float* Ain = (l==0)? h0 : r2;
      const float* g2  = (l==0)? nullptr : ln2g + (l-1)*DMODEL;
      const float* bb2 = (l==0)? nullptr : ln2b + (l-1)*DMODEL;
      float* Ast       = (l==0)? nullptr : hln;
      const float* res1= (l==0)? h0 : hln;

      gemm(Ain,DMODEL,g2,bb2,Ast,  Wq + (size_t)l*DMODEL*DMODEL, nullptr, nullptr,
           qb,0,1, DMODEL,DMODEL, qlo,qc, 0);
      gemm(Ain,DMODEL,g2,bb2,nullptr, Wk + (size_t)l*DMODEL*DMODEL, nullptr, nullptr,
           kb,0,1, DMODEL,DMODEL, klo,kc, 0);
      gemm(Ain,DMODEL,g2,bb2,nullptr, Wv + (size_t)l*DMODEL*DMODEL, nullptr, nullptr,
           vb,0,1, DMODEL,DMODEL, vlo,vc, 0);

      attn_k<<<dim3((ac+31)/32,NHEAD,NB),dim3(256),0,stream>>>(qb,kb,vb,att,alo,ac);

      gemm(att,DMODEL,nullptr,nullptr,nullptr, Wo + (size_t)l*DMODEL*DMODEL, nullptr, res1,
           r1,DMODEL,0, DMODEL,DMODEL, alo,ac, 0);
      gemm(r1,DMODEL, ln1g + l*DMODEL, ln1b + l*DMODEL, hp,
           W1 + (size_t)l*DFFN*DMODEL, b1 + l*DFFN, nullptr,
           fbuf,DFFN,0, DFFN,DMODEL, olo,oc, 1);
      gemm(fbuf,DFFN,nullptr,nullptr,nullptr, W2 + (size_t)l*DMODEL*DFFN, b2v + l*DMODEL, hp,
           r2,DMODEL,0, DMODEL,DFFN, olo,oc, 0);
    }

    ctx_k<<<dim3(16,NB),dim3(256),0,stream>>>(r2, ln2g + 3*DMODEL, ln2b + 3*DMODEL,
                                              Wr1, cb1, ctxt, ptr);
    for(int k=0;k<5;k++)
      refine_sub<<<dim3(4,NB),dim3(256),0,stream>>>(M1,ctxt,Wr2,br2,cur_x,curv,parts,k);
    finalize_k<<<dim3(NB),dim3(256),0,stream>>>(curv,parts,br2,W_emb,b_emb,cur_x,h0,out,s,ptr);
  }
}

// Round 2
// 6338.459 us; speedup vs baseline: 1.3335x; 1.3335x over previous
//
#include <hip/hip_runtime.h>
#include <math.h>

// ---------------- problem constants ----------------
namespace {
constexpr int NB = 4;       // batch
constexpr int SEQ = 128;    // total_len = TH + steps
constexpr int TH_ = 120;    // history length
constexpr int NSTEP = 8;
constexpr int DMODEL = 512;
constexpr int NHEAD = 8;
constexpr int DHEAD = 64;
constexpr int DFFN = 2048;
constexpr int DIN = 32;
constexpr float SCALE_EMB = 22.627416997969522f; // sqrt(512)
constexpr float LN_EPS = 1e-5f;
constexpr float NEGF = -3.4028234663852886e38f;  // jnp.finfo(f32).min
constexpr float PE_C = -0.017988946039015984f;   // -ln(10000)/512
}

using short8 = __attribute__((ext_vector_type(8))) short;
using f32x4  = __attribute__((ext_vector_type(4))) float;

// ---------------- device helpers ----------------
__device__ __forceinline__ float wave_sum(float v){
#pragma unroll
  for(int off=32;off;off>>=1) v += __shfl_xor(v,off,64);
  return v;
}
__device__ __forceinline__ float blk_sum(float v, float* scr){
  v = wave_sum(v);
  __syncthreads();
  if((threadIdx.x&63)==0) scr[threadIdx.x>>6]=v;
  __syncthreads();
  return scr[0]+scr[1]+scr[2]+scr[3];
}
__device__ __forceinline__ float gelu_t(float x){
  float t = 0.7978845608028654f*(x + 0.044715f*x*x*x);
  return 0.5f*x*(1.0f + tanhf(t));
}
__device__ __forceinline__ float pe_val(int t, int d){
  float div = expf((float)(d & ~1) * PE_C);
  float a = (float)t * div;
  return (d & 1) ? cosf(a) : sinf(a);
}
__device__ __forceinline__ unsigned short f2b(float f){
  union { float f; unsigned u; } c; c.f = f;
  unsigned u = c.u + 0x7FFFu + ((c.u>>16)&1u);
  return (unsigned short)(u>>16);
}
__device__ __forceinline__ short8 pack8(const float* f){
  short8 s;
#pragma unroll
  for(int i=0;i<8;i++) s[i] = (short)f2b(f[i]);
  return s;
}

// ---------------- h0 init ----------------
__global__ __launch_bounds__(256) void init_h0(const float* __restrict__ hist,
                                               const float* __restrict__ W_emb,
                                               const float* __restrict__ b_emb,
                                               float* __restrict__ h0){
  int bt = blockIdx.x;
  int b = bt >> 7, t = bt & 127;
  __shared__ float x[DIN];
  if(threadIdx.x < DIN)
    x[threadIdx.x] = (t < TH_) ? hist[((size_t)b*TH_ + t)*DIN + threadIdx.x] : 0.f;
  __syncthreads();
  for(int d = threadIdx.x; d < DMODEL; d += 256){
    float s = 0.f;
#pragma unroll 8
    for(int i=0;i<DIN;i++) s += W_emb[d*DIN+i]*x[i];
    h0[(size_t)bt*DMODEL + d] = SCALE_EMB*(s + b_emb[d]) + pe_val(t,d);
  }
}

// ---------------- M1 / cb1 / cur_x init ----------------
__global__ __launch_bounds__(256) void init_misc(const float* __restrict__ Wr1,
                                                 const float* __restrict__ W_emb,
                                                 const float* __restrict__ b_emb,
                                                 const float* __restrict__ br1,
                                                 const float* __restrict__ hist,
                                                 float* __restrict__ M1,
                                                 float* __restrict__ cb1,
                                                 float* __restrict__ cur_x){
  __shared__ float row[DMODEL];
  int j0 = blockIdx.x*8;
  for(int jj=0;jj<8;jj++){
    int j = j0+jj;
    for(int k=threadIdx.x;k<DMODEL;k+=256) row[k] = Wr1[(size_t)j*1024 + k];
    __syncthreads();
    if(threadIdx.x < DIN){
      int i = threadIdx.x; float s = 0.f;
      for(int k=0;k<DMODEL;k++) s += row[k]*W_emb[k*DIN+i];
      M1[j*DIN+i] = SCALE_EMB*s;
    } else if(threadIdx.x == DIN){
      float s=0.f;
      for(int k=0;k<DMODEL;k++) s += row[k]*b_emb[k];
      cb1[j] = br1[j] + SCALE_EMB*s;
    }
    __syncthreads();
  }
  if(blockIdx.x==0 && threadIdx.x<NB*DIN){
    int b = threadIdx.x>>5, i = threadIdx.x&31;
    cur_x[b*DIN+i] = hist[((size_t)b*TH_ + (TH_-1))*DIN + i];
  }
}

// ---------------- bf16 MFMA GEMM: C = act(LN?(A)@W^T + bias + resid) ---------------------
// block tile 32 rows x 128 cols, 4 waves; wave = 2 row-tiles x 2 col-tiles of 16x16.
// K-chunk 64. Weights converted fp32->bf16 during staging.
// c_mode: 0 plain [b*SEQ+t][c_rs]; 1 head-split; 2 fused QKV (Wa/Wb2/Wc by n>>9).
__global__ __launch_bounds__(256) void gemm_mfma(
    const float* __restrict__ A, int a_rs,
    const float* __restrict__ lng, const float* __restrict__ lnb,
    float* __restrict__ Ast,
    const float* __restrict__ Wa, const float* __restrict__ Wb2,
    const float* __restrict__ Wc,
    const float* __restrict__ bias, const float* __restrict__ resid,
    float* __restrict__ C, int c_rs, int c_mode,
    int K, int t_lo, int t_cnt, int act)
{
  int b = blockIdx.z;
  int n0 = blockIdx.x*128;
  int m0 = blockIdx.y*32;
  int tid = threadIdx.x;
  int w = tid>>6, ln = tid&63;
  __shared__ __align__(16) unsigned short As[32][72];
  __shared__ __align__(16) unsigned short Bs[128][72];
  __shared__ float mu_s[32], rs_s[32];
  int tmax = t_lo + t_cnt;

  const float* Wsrc; int nrow0;
  if(c_mode==2){ int which = n0>>9; Wsrc = (which==0?Wa:(which==1?Wb2:Wc)); nrow0 = n0&511; }
  else { Wsrc = Wa; nrow0 = n0; }

  if(lng){ // K == DMODEL when LN is applied
    for(int r=w;r<32;r+=4){
      int t = t_lo + m0 + r;
      float mu=0.f, rs=1.f;
      if(t<tmax){
        const float* ap = A + (size_t)(b*SEQ+t)*a_rs;
        float s=0.f;
        for(int k=ln;k<DMODEL;k+=64) s += ap[k];
        s = wave_sum(s); mu = s*(1.f/DMODEL);
        float v=0.f;
        for(int k=ln;k<DMODEL;k+=64){ float d0=ap[k]-mu; v+=d0*d0; }
        v = wave_sum(v); rs = rsqrtf(v*(1.f/DMODEL)+LN_EPS);
      }
      if(ln==0){ mu_s[r]=mu; rs_s[r]=rs; }
    }
    __syncthreads();
  }

  f32x4 acc[2][2];
#pragma unroll
  for(int i=0;i<2;i++)
#pragma unroll
    for(int j=0;j<2;j++) acc[i][j] = (f32x4){0.f,0.f,0.f,0.f};

  int ar = tid>>3, akq = (tid&7)*8;
  int fr = ln&15, fq = (ln>>4)*8;

  for(int k0=0;k0<K;k0+=64){
    { // stage A chunk (fp32 -> optional LN -> bf16)
      int t = t_lo + m0 + ar;
      float f[8];
      if(t<tmax){
        const float* ap = A + (size_t)(b*SEQ+t)*a_rs + k0 + akq;
        float4 v0 = *(const float4*)ap;
        float4 v1 = *(const float4*)(ap+4);
        f[0]=v0.x; f[1]=v0.y; f[2]=v0.z; f[3]=v0.w;
        f[4]=v1.x; f[5]=v1.y; f[6]=v1.z; f[7]=v1.w;
        if(lng){
          float mu=mu_s[ar], rs=rs_s[ar];
          int kb = k0+akq;
#pragma unroll
          for(int i=0;i<8;i++) f[i] = (f[i]-mu)*rs*lng[kb+i] + lnb[kb+i];
          if(Ast && blockIdx.x==0){
            float* dp = Ast + (size_t)(b*SEQ+t)*DMODEL + kb;
            *(float4*)dp     = make_float4(f[0],f[1],f[2],f[3]);
            *(float4*)(dp+4) = make_float4(f[4],f[5],f[6],f[7]);
          }
        }
      } else {
#pragma unroll
        for(int i=0;i<8;i++) f[i]=0.f;
      }
      *(short8*)&As[ar][akq] = pack8(f);
    }
    { // stage B chunk (fp32 weights -> bf16), 128 rows x 64 k
#pragma unroll
      for(int p=0;p<4;p++){
        int n = p*32 + ar;
        const float* wp = Wsrc + (size_t)(nrow0+n)*K + k0 + akq;
        float4 v0 = *(const float4*)wp;
        float4 v1 = *(const float4*)(wp+4);
        float f[8] = {v0.x,v0.y,v0.z,v0.w,v1.x,v1.y,v1.z,v1.w};
        *(short8*)&Bs[n][akq] = pack8(f);
      }
    }
    __syncthreads();
    short8 af[2][2], bf[2][2];
#pragma unroll
    for(int kf=0;kf<2;kf++){
#pragma unroll
      for(int rt=0;rt<2;rt++) af[rt][kf] = *(const short8*)&As[rt*16 + fr][kf*32 + fq];
#pragma unroll
      for(int ct=0;ct<2;ct++) bf[ct][kf] = *(const short8*)&Bs[32*w + ct*16 + fr][kf*32 + fq];
    }
#pragma unroll
    for(int kf=0;kf<2;kf++)
#pragma unroll
      for(int rt=0;rt<2;rt++)
#pragma unroll
        for(int ct=0;ct<2;ct++)
          acc[rt][ct] = __builtin_amdgcn_mfma_f32_16x16x32_bf16(af[rt][kf], bf[ct][kf], acc[rt][ct], 0, 0, 0);
    __syncthreads();
  }

#pragma unroll
  for(int rt=0;rt<2;rt++){
#pragma unroll
    for(int ct=0;ct<2;ct++){
      int n = n0 + 32*w + ct*16 + fr;
#pragma unroll
      for(int r=0;r<4;r++){
        int t = t_lo + m0 + rt*16 + (ln>>4)*4 + r;
        if(t >= tmax) continue;
        float v = acc[rt][ct][r];
        if(bias)  v += bias[n];
        if(resid) v += resid[(size_t)(b*SEQ+t)*DMODEL + n];
        if(act==1) v = gelu_t(v);
        if(c_mode==0)      C[(size_t)(b*SEQ+t)*c_rs + n] = v;
        else if(c_mode==1) C[((size_t)(b*NHEAD + (n>>6))*SEQ + t)*DHEAD + (n&63)] = v;
        else {
          int which = n>>9, rem = n&511;
          C[(size_t)which*(NB*SEQ*DMODEL) +
            ((size_t)(b*NHEAD + (rem>>6))*SEQ + t)*DHEAD + (rem&63)] = v;
        }
      }
    }
  }
}

// ---------------- small-row GEMM (<=9 rows/batch), fp32 ----------------------------------
__global__ __launch_bounds__(256) void gemm_rows(
    const float* __restrict__ A, int a_rs,
    const float* __restrict__ lng, const float* __restrict__ lnb,
    float* __restrict__ Ast,
    const float* __restrict__ W, const float* __restrict__ bias,
    const float* __restrict__ resid,
    float* __restrict__ C, int c_rs, int c_mode,
    int K, int t_lo, int t_cnt, int act)
{
  int b = blockIdx.y;
  int c0 = blockIdx.x*16;
  int tid = threadIdx.x;
  int kl = tid&15, cg = tid>>4;
  __shared__ float al[9][520];
  __shared__ float scr[4];
  int nr = t_cnt;  // <= 9

  if(lng){ // K == DMODEL
    for(int r=0;r<nr;r++){
      const float* ap = A + (size_t)(b*SEQ + t_lo + r)*a_rs;
      float s = 0.f;
      for(int k=tid;k<K;k+=256) s += ap[k];
      s = blk_sum(s, scr);
      float mu = s/(float)K;
      float v = 0.f;
      for(int k=tid;k<K;k+=256){ float d0 = ap[k]-mu; v += d0*d0; }
      v = blk_sum(v, scr);
      float rs = rsqrtf(v/(float)K + LN_EPS);
      for(int k=tid;k<K;k+=256){
        float x = (ap[k]-mu)*rs*lng[k] + lnb[k];
        al[r][k] = x;
        if(Ast && blockIdx.x==0) Ast[(size_t)(b*SEQ+t_lo+r)*DMODEL + k] = x;
      }
    }
    __syncthreads();
  }

  float acc[9];
#pragma unroll
  for(int r=0;r<9;r++) acc[r]=0.f;
  const float* wp = W + (size_t)(c0+cg)*K;
  if(lng){
    for(int k=kl;k<K;k+=16){
      float w0 = wp[k];
      for(int r=0;r<nr;r++) acc[r] += al[r][k]*w0;
    }
  } else {
    for(int k=kl;k<K;k+=16){
      float w0 = wp[k];
      for(int r=0;r<nr;r++) acc[r] += A[(size_t)(b*SEQ+t_lo+r)*a_rs + k]*w0;
    }
  }
#pragma unroll
  for(int off=1;off<16;off<<=1)
    for(int r=0;r<9;r++) acc[r] += __shfl_xor(acc[r],off,64);
  if(kl==0){
    int n = c0+cg;
    for(int r=0;r<nr;r++){
      float v = acc[r];
      if(bias)  v += bias[n];
      if(resid) v += resid[(size_t)(b*SEQ+t_lo+r)*DMODEL + n];
      if(act==1) v = gelu_t(v);
      int t = t_lo + r;
      if(c_mode==0) C[(size_t)(b*SEQ+t)*c_rs + n] = v;
      else          C[((size_t)(b*NHEAD + (n>>6))*SEQ + t)*DHEAD + (n&63)] = v;
    }
  }
}

// ---------------- fused attention per (b,h) ----------------------------------------------
__global__ __launch_bounds__(256) void attn_k(const float* __restrict__ qb,
                                              const float* __restrict__ kb,
                                              const float* __restrict__ vb,
                                              float* __restrict__ att,
                                              int t_lo, int t_cnt){
  int b = blockIdx.z, h = blockIdx.y;
  int r0 = blockIdx.x*32;
  int nr = min(32, t_cnt - r0);
  const float* Kh = kb + (size_t)(b*NHEAD+h)*SEQ*DHEAD;
  const float* Vh = vb + (size_t)(b*NHEAD+h)*SEQ*DHEAD;
  const float* Qh = qb + (size_t)(b*NHEAD+h)*SEQ*DHEAD;
  __shared__ float kv[SEQ][DHEAD];
  __shared__ float wsm[32][132];
  __shared__ float qs[32][DHEAD];
  int tid = threadIdx.x;
  int d = tid&63, rr = tid>>6;

  for(int k=rr;k<SEQ;k+=4) kv[k][d ^ (k&60)] = Kh[k*DHEAD + d];
  for(int r=rr;r<nr;r+=4)  qs[r][d] = Qh[(size_t)(t_lo+r0+r)*DHEAD + d];
  __syncthreads();

  {
    int k = tid&127, g = tid>>7;
    for(int r=g;r<nr;r+=2){
      int t = t_lo + r0 + r;
      float lg = NEGF;
      if(k > t){
        int sw = k&60;
        float s = 0.f;
#pragma unroll 8
        for(int dd=0;dd<DHEAD;dd++) s += qs[r][dd]*kv[k][dd^sw];
        lg = s*0.125f;
      }
      wsm[r][k] = lg;
    }
  }
  __syncthreads();

  {
    int l2 = tid&63, wv = tid>>6;
    for(int r=wv;r<nr;r+=4){
      float l0 = wsm[r][l2], l1 = wsm[r][l2+64];
      float m = fmaxf(l0,l1);
#pragma unroll
      for(int off=32;off;off>>=1) m = fmaxf(m, __shfl_xor(m,off,64));
      float e0 = expf(l0-m), e1 = expf(l1-m);
      float s = e0+e1;
      s = wave_sum(s);
      float inv = 1.f/s;
      wsm[r][l2] = e0*inv; wsm[r][l2+64] = e1*inv;
    }
  }
  __syncthreads();

  for(int k=rr;k<SEQ;k+=4) kv[k][d] = Vh[k*DHEAD + d];
  __syncthreads();

  {
    int dq = (tid&15)*4, rg = tid>>4;
    for(int r=rg;r<nr;r+=16){
      float4 acc = make_float4(0.f,0.f,0.f,0.f);
      for(int k=0;k<SEQ;k++){
        float w0 = wsm[r][k];
        float4 v = *(const float4*)&kv[k][dq];
        acc.x += w0*v.x; acc.y += w0*v.y; acc.z += w0*v.z; acc.w += w0*v.w;
      }
      int t = t_lo + r0 + r;
      *(float4*)(att + (size_t)(b*SEQ+t)*DMODEL + h*DHEAD + dq) = acc;
    }
  }
}

// ---------------- ctx = LN2_3(r2[ptr-1]); ctxt = Wr1b@ctx + cb1 --------------------------
__global__ __launch_bounds__(256) void ctx_k(const float* __restrict__ r2,
                                             const float* __restrict__ g2,
                                             const float* __restrict__ b2,
                                             const float* __restrict__ Wr1,
                                             const float* __restrict__ cb1,
                                             float* __restrict__ ctxt, int ptr){
  int b = blockIdx.y; int j0 = blockIdx.x*128;
  __shared__ float raw[DMODEL], ctx[DMODEL], scr[4];
  int tid = threadIdx.x;
  const float* rp = r2 + (size_t)(b*SEQ + ptr-1)*DMODEL;
  for(int k=tid;k<DMODEL;k+=256) raw[k]=rp[k];
  __syncthreads();
  float s = 0.f;
  for(int k=tid;k<DMODEL;k+=256) s += raw[k];
  s = blk_sum(s, scr);
  float mu = s/(float)DMODEL;
  float v = 0.f;
  for(int k=tid;k<DMODEL;k+=256){ float d0 = raw[k]-mu; v += d0*d0; }
  v = blk_sum(v, scr);
  float rs = rsqrtf(v/(float)DMODEL + LN_EPS);
  for(int k=tid;k<DMODEL;k+=256) ctx[k] = (raw[k]-mu)*rs*g2[k] + b2[k];
  __syncthreads();
  int wv = tid>>6, l2 = tid&63;
  for(int jj=wv;jj<128;jj+=4){
    int j = j0+jj;
    const float* wp = Wr1 + (size_t)j*1024 + 512;
    float acc = 0.f;
#pragma unroll
    for(int q=0;q<8;q++){ int k = l2 + 64*q; acc += wp[k]*ctx[k]; }
    acc = wave_sum(acc);
    if(l2==0) ctxt[b*DFFN + j] = acc + cb1[j];
  }
}

// ---------------- refine substep ---------------------------------------------------------
__global__ __launch_bounds__(256) void refine_sub(const float* __restrict__ M1,
                                                  const float* __restrict__ ctxt,
                                                  const float* __restrict__ Wr2,
                                                  const float* __restrict__ br2,
                                                  const float* __restrict__ cur_x,
                                                  float* __restrict__ curv,
                                                  float* __restrict__ parts, int sub){
  int b = blockIdx.y, wg = blockIdx.x;
  __shared__ float cur_s[DIN], g_s[512];
  int tid = threadIdx.x;
  if(tid < DIN){
    int i = tid; float c;
    if(sub==0) c = cur_x[b*DIN+i];
    else {
      int pb = (sub-1)&1;
      c = curv[(pb*NB+b)*DIN + i];
      float d = br2[i];
      for(int w=0;w<4;w++) d += parts[((pb*NB+b)*4+w)*DIN + i];
      c += d;
    }
    cur_s[i] = c;
    if(wg==0) curv[((sub&1)*NB+b)*DIN + i] = c;
  }
  __syncthreads();
  int jbase = wg*512;
  for(int jj=tid;jj<512;jj+=256){
    int j = jbase+jj;
    float u = ctxt[b*DFFN + j];
    const float* mp = M1 + (size_t)j*DIN;
#pragma unroll 8
    for(int i=0;i<DIN;i++) u += mp[i]*cur_s[i];
    g_s[jj] = gelu_t(u);
  }
  __syncthreads();
  int wv = tid>>6, l2 = tid&63;
  for(int q=0;q<8;q++){
    int i = wv*8 + q;
    float acc = 0.f;
#pragma unroll
    for(int p=0;p<8;p++){ int jj = l2 + 64*p; acc += Wr2[(size_t)i*DFFN + jbase + jj]*g_s[jj]; }
    acc = wave_sum(acc);
    if(l2==0) parts[((sub&1)*NB+b)*4*DIN + wg*DIN + i] = acc;
  }
}

// ---------------- finalize step ----------------------------------------------------------
__global__ __launch_bounds__(256) void finalize_k(const float* __restrict__ curv,
                                                  const float* __restrict__ parts,
                                                  const float* __restrict__ br2,
                                                  const float* __restrict__ W_emb,
                                                  const float* __restrict__ b_emb,
                                                  float* __restrict__ cur_x,
                                                  float* __restrict__ h0,
                                                  float* __restrict__ out,
                                                  int s, int ptr){
  int b = blockIdx.x; int tid = threadIdx.x;
  __shared__ float c5[DIN];
  if(tid < DIN){
    int i = tid;
    float c = curv[(0*NB+b)*DIN + i];
    float d = br2[i];
    for(int w=0;w<4;w++) d += parts[((0*NB+b)*4+w)*DIN + i];
    c += d;
    c5[i] = c;
    out[(b*NSTEP + s)*DIN + i] = c;
    cur_x[b*DIN + i] = c;
  }
  __syncthreads();
  for(int d0=tid; d0<DMODEL; d0+=256){
    float s2 = 0.f;
#pragma unroll 8
    for(int i=0;i<DIN;i++) s2 += W_emb[d0*DIN+i]*c5[i];
    h0[(size_t)(b*SEQ + ptr)*DMODEL + d0] = SCALE_EMB*(s2 + b_emb[d0]) + pe_val(ptr, d0);
  }
}

// ---------------- host ----------------
extern "C" void kernel_launch(void* const* d_in, const int* in_sizes, int n_in,
                              void* d_out, int out_size, void* d_ws, size_t ws_size,
                              hipStream_t stream) {
  (void)in_sizes; (void)n_in; (void)out_size; (void)ws_size;
  const float* hist = (const float*)d_in[0];
  const float* W_emb= (const float*)d_in[2];
  const float* b_emb= (const float*)d_in[3];
  const float* Wq   = (const float*)d_in[4];
  const float* Wk   = (const float*)d_in[5];
  const float* Wv   = (const float*)d_in[6];
  const float* Wo   = (const float*)d_in[7];
  const float* ln1g = (const float*)d_in[8];
  const float* ln1b = (const float*)d_in[9];
  const float* W1   = (const float*)d_in[10];
  const float* b1   = (const float*)d_in[11];
  const float* W2   = (const float*)d_in[12];
  const float* b2v  = (const float*)d_in[13];
  const float* ln2g = (const float*)d_in[14];
  const float* ln2b = (const float*)d_in[15];
  const float* Wr1  = (const float*)d_in[16];
  const float* br1  = (const float*)d_in[17];
  const float* Wr2  = (const float*)d_in[18];
  const float* br2  = (const float*)d_in[19];
  float* out = (float*)d_out;
  float* ws  = (float*)d_ws;

  const size_t SZ_BTD = (size_t)NB*SEQ*DMODEL;   // 262144
  float* h0   = ws;
  float* r1   = h0   + SZ_BTD;
  float* r2   = r1   + SZ_BTD;
  float* hln  = r2   + SZ_BTD;
  float* hp   = hln  + SZ_BTD;
  float* att  = hp   + SZ_BTD;
  float* qb   = att  + SZ_BTD;    // q,k,v contiguous: [b][h][t][64] each
  float* kb   = qb   + SZ_BTD;
  float* vb   = kb   + SZ_BTD;
  float* fbuf = vb   + SZ_BTD;    // [b][t][2048]
  float* M1   = fbuf + (size_t)NB*SEQ*DFFN;
  float* cb1  = M1   + (size_t)DFFN*DIN;
  float* ctxt = cb1  + DFFN;
  float* curv = ctxt + (size_t)NB*DFFN;
  float* parts= curv + 2*NB*DIN;
  float* cur_x= parts+ 2*NB*4*DIN;

  init_h0<<<dim3(NB*SEQ),dim3(256),0,stream>>>(hist,W_emb,b_emb,h0);
  init_misc<<<dim3(256),dim3(256),0,stream>>>(Wr1,W_emb,b_emb,br1,hist,M1,cb1,cur_x);

  const size_t OD = (size_t)DMODEL*DMODEL;
  const size_t OF = (size_t)DFFN*DMODEL;

  auto rows = [&](const float* A,int a_rs,const float* g,const float* bb,float* Ast,
                  const float* W,const float* bias,const float* resid,
                  float* C,int c_rs,int c_mode,int N,int K,int lo,int cnt,int act){
    dim3 gd(N/16,NB);
    gemm_rows<<<gd,dim3(256),0,stream>>>(A,a_rs,g,bb,Ast,W,bias,resid,C,c_rs,c_mode,K,lo,cnt,act);
  };
  auto mfma = [&](const float* A,int a_rs,const float* g,const float* bb,float* Ast,
                  const float* W0,const float* W1p,const float* W2p,
                  const float* bias,const float* resid,
                  float* C,int c_rs,int c_mode,int N,int K,int lo,int cnt,int act){
    dim3 gd(N/128,(cnt+31)/32,NB);
    gemm_mfma<<<gd,dim3(256),0,stream>>>(A,a_rs,g,bb,Ast,W0,W1p,W2p,bias,resid,C,c_rs,c_mode,K,lo,cnt,act);
  };

  for(int s=0;s<NSTEP;s++){
    int ptr = TH_ + s;
    for(int l=0;l<4;l++){
      const float* Ain = (l==0)? h0 : r2;
      const float* g2  = (l==0)? nullptr : ln2g + (l-1)*DMODEL;
      const float* bb2 = (l==0)? nullptr : ln2b + (l-1)*DMODEL;
      float* Ast       = (l==0)? nullptr : hln;
      const float* res1= (l==0)? h0 : hln;

      if(l < 2){
        // fused QKV (N=1536), full 128 rows
        mfma(Ain,DMODEL,g2,bb2,Ast, Wq+l*OD, Wk+l*OD, Wv+l*OD, nullptr,nullptr,
             qb,0,2, 3*DMODEL,DMODEL, 0,SEQ, 0);
        attn_k<<<dim3(4,NHEAD,NB),dim3(256),0,stream>>>(qb,kb,vb,att,0,SEQ);
        mfma(att,DMODEL,nullptr,nullptr,nullptr, Wo+l*OD,nullptr,nullptr, nullptr,res1,
             r1,DMODEL,0, DMODEL,DMODEL, 0,SEQ, 0);
        mfma(r1,DMODEL, ln1g+l*DMODEL, ln1b+l*DMODEL, hp, W1+l*OF,nullptr,nullptr,
             b1+l*DFFN, nullptr, fbuf,DFFN,0, DFFN,DMODEL, 0,SEQ, 1);
        mfma(fbuf,DFFN, nullptr,nullptr,nullptr, W2+l*OF,nullptr,nullptr,
             b2v+l*DMODEL, hp, r2,DMODEL,0, DMODEL,DFFN, 0,SEQ, 0);
      } else {
        int qlo,qc,klo,kc,vlo,vc,alo,ac;
        if(l==2){
          qlo=ptr-1; qc=SEQ-(ptr-1); klo=ptr; kc=SEQ-ptr; vlo=0; vc=SEQ;
          alo=ptr-1; ac=SEQ-(ptr-1);
        } else {
          qlo=ptr-1; qc=1; klo=ptr; kc=SEQ-ptr; vlo=ptr; vc=SEQ-ptr;
          alo=ptr-1; ac=1;
        }
        rows(Ain,DMODEL,g2,bb2,Ast, Wq+l*OD, nullptr,nullptr, qb,0,1, DMODEL,DMODEL, qlo,qc, 0);
        rows(Ain,DMODEL,g2,bb2,nullptr, Wk+l*OD, nullptr,nullptr, kb,0,1, DMODEL,DMODEL, klo,kc, 0);
        if(vc > 9)
          mfma(Ain,DMODEL,g2,bb2,nullptr, Wv+l*OD,nullptr,nullptr, nullptr,nullptr,
               vb,0,1, DMODEL,DMODEL, vlo,vc, 0);
        else
          rows(Ain,DMODEL,g2,bb2,nullptr, Wv+l*OD, nullptr,nullptr, vb,0,1, DMODEL,DMODEL, vlo,vc, 0);

        attn_k<<<dim3((ac+31)/32,NHEAD,NB),dim3(256),0,stream>>>(qb,kb,vb,att,alo,ac);

        rows(att,DMODEL,nullptr,nullptr,nullptr, Wo+l*OD, nullptr, res1,
             r1,DMODEL,0, DMODEL,DMODEL, alo,ac, 0);
        rows(r1,DMODEL, ln1g+l*DMODEL, ln1b+l*DMODEL, hp, W1+l*OF, b1+l*DFFN, nullptr,
             fbuf,DFFN,0, DFFN,DMODEL, alo,ac, 1);
        rows(fbuf,DFFN, nullptr,nullptr,nullptr, W2+l*OF, b2v+l*DMODEL, hp,
             r2,DMODEL,0, DMODEL,DFFN, alo,ac, 0);
      }
    }

    ctx_k<<<dim3(16,NB),dim3(256),0,stream>>>(r2, ln2g + 3*DMODEL, ln2b + 3*DMODEL,
                                              Wr1, cb1, ctxt, ptr);
    for(int k=0;k<5;k++)
      refine_sub<<<dim3(4,NB),dim3(256),0,stream>>>(M1,ctxt,Wr2,br2,cur_x,curv,parts,k);
    finalize_k<<<dim3(NB),dim3(256),0,stream>>>(curv,parts,br2,W_emb,b_emb,cur_x,h0,out,s,ptr);
  }
}

// Round 3
// 4746.011 us; speedup vs baseline: 1.7809x; 1.3355x over previous
//
#include <hip/hip_runtime.h>
#include <math.h>

// ---------------- problem constants ----------------
namespace {
constexpr int NB = 4;
constexpr int SEQ = 128;
constexpr int TH_ = 120;
constexpr int NSTEP = 8;
constexpr int DMODEL = 512;
constexpr int NHEAD = 8;
constexpr int DHEAD = 64;
constexpr int DFFN = 2048;
constexpr int DIN = 32;
constexpr int MROWS = NB*SEQ;   // 512 flattened rows
constexpr float SCALE_EMB = 22.627416997969522f; // sqrt(512)
constexpr float LN_EPS = 1e-5f;
constexpr float NEGF = -3.4028234663852886e38f;  // jnp.finfo(f32).min
constexpr float PE_C = -0.017988946039015984f;   // -ln(10000)/512
}

using short8 = __attribute__((ext_vector_type(8))) short;
using f32x4  = __attribute__((ext_vector_type(4))) float;

// ---------------- device helpers ----------------
__device__ __forceinline__ float wave_sum(float v){
#pragma unroll
  for(int off=32;off;off>>=1) v += __shfl_xor(v,off,64);
  return v;
}
__device__ __forceinline__ float blk_sum(float v, float* scr){
  v = wave_sum(v);
  __syncthreads();
  if((threadIdx.x&63)==0) scr[threadIdx.x>>6]=v;
  __syncthreads();
  return scr[0]+scr[1]+scr[2]+scr[3];
}
__device__ __forceinline__ float gelu_t(float x){
  float t = 0.7978845608028654f*(x + 0.044715f*x*x*x);
  return 0.5f*x*(1.0f + tanhf(t));
}
__device__ __forceinline__ float pe_val(int t, int d){
  float div = expf((float)(d & ~1) * PE_C);
  float a = (float)t * div;
  return (d & 1) ? cosf(a) : sinf(a);
}
__device__ __forceinline__ unsigned short f2b(float f){
  union { float f; unsigned u; } c; c.f = f;
  unsigned u = c.u + 0x7FFFu + ((c.u>>16)&1u);
  return (unsigned short)(u>>16);
}
__device__ __forceinline__ short8 pack8(const float* f){
  short8 s;
#pragma unroll
  for(int i=0;i<8;i++) s[i] = (short)f2b(f[i]);
  return s;
}

// ---------------- one-time: convert all weights to bf16 ----------------
__global__ __launch_bounds__(256) void conv_w(const float* __restrict__ Wq,
                                              const float* __restrict__ Wk,
                                              const float* __restrict__ Wv,
                                              const float* __restrict__ Wo,
                                              const float* __restrict__ W1,
                                              const float* __restrict__ W2,
                                              unsigned short* __restrict__ dst){
  size_t base = ((size_t)blockIdx.x*256 + threadIdx.x)*8;
  if(base >= 12582912u) return;
  const float* src; size_t off;
  if(base < 1048576u){ src=Wq; off=base; }
  else if(base < 2097152u){ src=Wk; off=base-1048576u; }
  else if(base < 3145728u){ src=Wv; off=base-2097152u; }
  else if(base < 4194304u){ src=Wo; off=base-3145728u; }
  else if(base < 8388608u){ src=W1; off=base-4194304u; }
  else { src=W2; off=base-8388608u; }
  float4 a = *(const float4*)(src+off);
  float4 b = *(const float4*)(src+off+4);
  float f[8] = {a.x,a.y,a.z,a.w,b.x,b.y,b.z,b.w};
  *(short8*)(dst + base) = pack8(f);
}

// ---------------- h0 init (fp32 + bf16) ----------------
__global__ __launch_bounds__(256) void init_h0(const float* __restrict__ hist,
                                               const float* __restrict__ W_emb,
                                               const float* __restrict__ b_emb,
                                               float* __restrict__ h0,
                                               unsigned short* __restrict__ h0b){
  int bt = blockIdx.x;
  int b = bt >> 7, t = bt & 127;
  __shared__ float x[DIN];
  if(threadIdx.x < DIN)
    x[threadIdx.x] = (t < TH_) ? hist[((size_t)b*TH_ + t)*DIN + threadIdx.x] : 0.f;
  __syncthreads();
  for(int d = threadIdx.x; d < DMODEL; d += 256){
    float s = 0.f;
#pragma unroll 8
    for(int i=0;i<DIN;i++) s += W_emb[d*DIN+i]*x[i];
    float v = SCALE_EMB*(s + b_emb[d]) + pe_val(t,d);
    h0[(size_t)bt*DMODEL + d] = v;
    h0b[(size_t)bt*DMODEL + d] = f2b(v);
  }
}

// ---------------- M1 / cb1 / cur_x init ----------------
__global__ __launch_bounds__(256) void init_misc(const float* __restrict__ Wr1,
                                                 const float* __restrict__ W_emb,
                                                 const float* __restrict__ b_emb,
                                                 const float* __restrict__ br1,
                                                 const float* __restrict__ hist,
                                                 float* __restrict__ M1,
                                                 float* __restrict__ cb1,
                                                 float* __restrict__ cur_x){
  __shared__ float row[DMODEL];
  int j0 = blockIdx.x*8;
  for(int jj=0;jj<8;jj++){
    int j = j0+jj;
    for(int k=threadIdx.x;k<DMODEL;k+=256) row[k] = Wr1[(size_t)j*1024 + k];
    __syncthreads();
    if(threadIdx.x < DIN){
      int i = threadIdx.x; float s = 0.f;
      for(int k=0;k<DMODEL;k++) s += row[k]*W_emb[k*DIN+i];
      M1[j*DIN+i] = SCALE_EMB*s;
    } else if(threadIdx.x == DIN){
      float s=0.f;
      for(int k=0;k<DMODEL;k++) s += row[k]*b_emb[k];
      cb1[j] = br1[j] + SCALE_EMB*s;
    }
    __syncthreads();
  }
  if(blockIdx.x==0 && threadIdx.x<NB*DIN){
    int b = threadIdx.x>>5, i = threadIdx.x&31;
    cur_x[b*DIN+i] = hist[((size_t)b*TH_ + (TH_-1))*DIN + i];
  }
}

// ---------------- LN pass: Y = LN(X)*g+b (fp32) and bf16 copy ----------------
__global__ __launch_bounds__(256) void lnpass(const float* __restrict__ X,
                                              const float* __restrict__ g,
                                              const float* __restrict__ bta,
                                              float* __restrict__ Y,
                                              unsigned short* __restrict__ Yb){
  int row = blockIdx.x*4 + (threadIdx.x>>6);
  int l = threadIdx.x&63;
  const float* xp = X + (size_t)row*DMODEL + l*8;
  float4 x0 = *(const float4*)xp;
  float4 x1 = *(const float4*)(xp+4);
  float f[8] = {x0.x,x0.y,x0.z,x0.w,x1.x,x1.y,x1.z,x1.w};
  float s = 0.f;
#pragma unroll
  for(int i=0;i<8;i++) s += f[i];
  s = wave_sum(s);
  float mu = s*(1.f/DMODEL);
  float v = 0.f;
#pragma unroll
  for(int i=0;i<8;i++){ float d0=f[i]-mu; v += d0*d0; }
  v = wave_sum(v);
  float rs = rsqrtf(v*(1.f/DMODEL) + LN_EPS);
#pragma unroll
  for(int i=0;i<8;i++){
    int c = l*8+i;
    f[i] = (f[i]-mu)*rs*g[c] + bta[c];
  }
  float* yp = Y + (size_t)row*DMODEL + l*8;
  *(float4*)yp     = make_float4(f[0],f[1],f[2],f[3]);
  *(float4*)(yp+4) = make_float4(f[4],f[5],f[6],f[7]);
  *(short8*)(Yb + (size_t)row*DMODEL + l*8) = pack8(f);
}

// ---------------- pure bf16 MFMA GEMM over flattened M=512 ----------------
// block tile 64 rows x 128 cols, 4 waves; wave = 4 row-tiles x 2 col-tiles (16x16).
// c_mode: 0 -> Cf fp32 [row][c_rs] (+bias,+resid,+act)
//         1 -> Cb bf16 [row][c_rs] (+bias,+act)
//         2 -> fused QKV scatter fp32 to Cf (qb|kb|vb by n>>9), [b][h][t][64]
__global__ __launch_bounds__(256) void gemm_bf(
    const unsigned short* __restrict__ A16, int Ka,
    const unsigned short* __restrict__ Wa,
    const unsigned short* __restrict__ Wb,
    const unsigned short* __restrict__ Wc,
    const float* __restrict__ bias, const float* __restrict__ resid,
    float* __restrict__ Cf, unsigned short* __restrict__ Cb,
    int c_rs, int c_mode, int act)
{
  int n0 = blockIdx.x*128;
  int m0 = blockIdx.y*64;
  int tid = threadIdx.x, w = tid>>6, ln = tid&63;
  __shared__ __align__(16) unsigned short As[64][72];
  __shared__ __align__(16) unsigned short Bs[128][72];

  const unsigned short* Wsrc; int nrow0;
  if(c_mode==2){ int which = n0>>9; Wsrc = (which==0?Wa:(which==1?Wb:Wc)); nrow0 = n0&511; }
  else { Wsrc = Wa; nrow0 = n0; }

  f32x4 acc[4][2];
#pragma unroll
  for(int i=0;i<4;i++)
#pragma unroll
    for(int j=0;j<2;j++) acc[i][j] = (f32x4){0.f,0.f,0.f,0.f};

  int fr = ln&15, fq = (ln>>4)*8;
  int arow = tid>>2, akq = (tid&3)*16;
  int brow = tid>>1, bkq = (tid&1)*32;

  for(int k0=0;k0<Ka;k0+=64){
    const unsigned short* ap = A16 + (size_t)(m0+arow)*Ka + k0 + akq;
    short8 a0 = *(const short8*)ap;
    short8 a1 = *(const short8*)(ap+8);
    const unsigned short* bp = Wsrc + (size_t)(nrow0+brow)*Ka + k0 + bkq;
    short8 b0 = *(const short8*)bp;
    short8 b1 = *(const short8*)(bp+8);
    short8 b2 = *(const short8*)(bp+16);
    short8 b3 = *(const short8*)(bp+24);
    *(short8*)&As[arow][akq]   = a0;
    *(short8*)&As[arow][akq+8] = a1;
    *(short8*)&Bs[brow][bkq]    = b0;
    *(short8*)&Bs[brow][bkq+8]  = b1;
    *(short8*)&Bs[brow][bkq+16] = b2;
    *(short8*)&Bs[brow][bkq+24] = b3;
    __syncthreads();
    short8 af[4][2], bf[2][2];
#pragma unroll
    for(int kf=0;kf<2;kf++){
#pragma unroll
      for(int rt=0;rt<4;rt++) af[rt][kf] = *(const short8*)&As[rt*16 + fr][kf*32 + fq];
#pragma unroll
      for(int ct=0;ct<2;ct++) bf[ct][kf] = *(const short8*)&Bs[32*w + ct*16 + fr][kf*32 + fq];
    }
#pragma unroll
    for(int kf=0;kf<2;kf++)
#pragma unroll
      for(int rt=0;rt<4;rt++)
#pragma unroll
        for(int ct=0;ct<2;ct++)
          acc[rt][ct] = __builtin_amdgcn_mfma_f32_16x16x32_bf16(af[rt][kf], bf[ct][kf], acc[rt][ct], 0, 0, 0);
    __syncthreads();
  }

#pragma unroll
  for(int rt=0;rt<4;rt++){
#pragma unroll
    for(int ct=0;ct<2;ct++){
      int n = n0 + 32*w + ct*16 + fr;
#pragma unroll
      for(int r=0;r<4;r++){
        int row = m0 + rt*16 + (ln>>4)*4 + r;
        float v = acc[rt][ct][r];
        if(bias)  v += bias[n];
        if(resid) v += resid[(size_t)row*DMODEL + n];
        if(act==1) v = gelu_t(v);
        if(c_mode==0)      Cf[(size_t)row*c_rs + n] = v;
        else if(c_mode==1) Cb[(size_t)row*c_rs + n] = f2b(v);
        else {
          int which = n>>9, rem = n&511;
          int b = row>>7, t = row&127;
          Cf[(size_t)which*(MROWS*DMODEL) +
             ((size_t)(b*NHEAD + (rem>>6))*SEQ + t)*DHEAD + (rem&63)] = v;
        }
      }
    }
  }
}

// ---------------- fused attention per (b,h); full 128 rows; writes bf16 ------------------
__global__ __launch_bounds__(256) void attn_k(const float* __restrict__ qb,
                                              const float* __restrict__ kb,
                                              const float* __restrict__ vb,
                                              unsigned short* __restrict__ attb){
  int b = blockIdx.z, h = blockIdx.y;
  int r0 = blockIdx.x*32;
  const float* Kh = kb + (size_t)(b*NHEAD+h)*SEQ*DHEAD;
  const float* Vh = vb + (size_t)(b*NHEAD+h)*SEQ*DHEAD;
  const float* Qh = qb + (size_t)(b*NHEAD+h)*SEQ*DHEAD;
  __shared__ float kv[SEQ][DHEAD];
  __shared__ float wsm[32][132];
  __shared__ float qs[32][68];
  int tid = threadIdx.x;
  int d = tid&63, rr = tid>>6;

  for(int k=rr;k<SEQ;k+=4) kv[k][d ^ (k&60)] = Kh[k*DHEAD + d];
  for(int r=rr;r<32;r+=4)  qs[r][d] = Qh[(size_t)(r0+r)*DHEAD + d];
  __syncthreads();

  { // logits: 2 rows x 8 keys per thread, float4 LDS reads
    int rp = tid>>4;        // 0..15 -> rows 2rp, 2rp+1
    int kg = tid&15;        // keys 8kg..8kg+7
    float acc[2][8];
#pragma unroll
    for(int i=0;i<2;i++)
#pragma unroll
      for(int kk=0;kk<8;kk++) acc[i][kk]=0.f;
#pragma unroll 4
    for(int d4=0;d4<16;d4++){
      float4 q0 = *(const float4*)&qs[2*rp][d4*4];
      float4 q1 = *(const float4*)&qs[2*rp+1][d4*4];
#pragma unroll
      for(int kk=0;kk<8;kk++){
        int k = 8*kg + kk;
        int off = (d4*4) ^ (k&60);
        float4 kv4 = *(const float4*)&kv[k][off];
        acc[0][kk] += q0.x*kv4.x + q0.y*kv4.y + q0.z*kv4.z + q0.w*kv4.w;
        acc[1][kk] += q1.x*kv4.x + q1.y*kv4.y + q1.z*kv4.z + q1.w*kv4.w;
      }
    }
#pragma unroll
    for(int i=0;i<2;i++){
      int t = r0 + 2*rp + i;
#pragma unroll
      for(int kk=0;kk<8;kk++){
        int k = 8*kg + kk;
        wsm[2*rp+i][k] = (k > t) ? acc[i][kk]*0.125f : NEGF;
      }
    }
  }
  __syncthreads();

  { // softmax per row (all-masked row -> uniform 1/128, faithful to jnp)
    int l2 = tid&63, wv = tid>>6;
    for(int r=wv;r<32;r+=4){
      float l0 = wsm[r][l2], l1 = wsm[r][l2+64];
      float m = fmaxf(l0,l1);
#pragma unroll
      for(int off=32;off;off>>=1) m = fmaxf(m, __shfl_xor(m,off,64));
      float e0 = expf(l0-m), e1 = expf(l1-m);
      float s = e0+e1;
      s = wave_sum(s);
      float inv = 1.f/s;
      wsm[r][l2] = e0*inv; wsm[r][l2+64] = e1*inv;
    }
  }
  __syncthreads();

  for(int k=rr;k<SEQ;k+=4) kv[k][d] = Vh[k*DHEAD + d];   // overwrite with V
  __syncthreads();

  { // out = w @ V, pack bf16
    int dq = (tid&15)*4, rg = tid>>4;
    for(int r=rg;r<32;r+=16){
      float4 acc2 = make_float4(0.f,0.f,0.f,0.f);
      for(int k=0;k<SEQ;k++){
        float w0 = wsm[r][k];
        float4 v = *(const float4*)&kv[k][dq];
        acc2.x += w0*v.x; acc2.y += w0*v.y; acc2.z += w0*v.z; acc2.w += w0*v.w;
      }
      int row = b*SEQ + r0 + r;
      unsigned short* op = attb + (size_t)row*DMODEL + h*DHEAD + dq;
      op[0]=f2b(acc2.x); op[1]=f2b(acc2.y); op[2]=f2b(acc2.z); op[3]=f2b(acc2.w);
    }
  }
}

// ---------------- ctx = LN2_3(r2[ptr-1]); ctxt = Wr1b@ctx + cb1 --------------------------
__global__ __launch_bounds__(256) void ctx_k(const float* __restrict__ r2,
                                             const float* __restrict__ g2,
                                             const float* __restrict__ b2,
                                             const float* __restrict__ Wr1,
                                             const float* __restrict__ cb1,
                                             float* __restrict__ ctxt, int ptr){
  int b = blockIdx.y; int j0 = blockIdx.x*128;
  __shared__ float raw[DMODEL], ctx[DMODEL], scr[4];
  int tid = threadIdx.x;
  const float* rp = r2 + (size_t)(b*SEQ + ptr-1)*DMODEL;
  for(int k=tid;k<DMODEL;k+=256) raw[k]=rp[k];
  __syncthreads();
  float s = 0.f;
  for(int k=tid;k<DMODEL;k+=256) s += raw[k];
  s = blk_sum(s, scr);
  float mu = s/(float)DMODEL;
  float v = 0.f;
  for(int k=tid;k<DMODEL;k+=256){ float d0 = raw[k]-mu; v += d0*d0; }
  v = blk_sum(v, scr);
  float rs = rsqrtf(v/(float)DMODEL + LN_EPS);
  for(int k=tid;k<DMODEL;k+=256) ctx[k] = (raw[k]-mu)*rs*g2[k] + b2[k];
  __syncthreads();
  int wv = tid>>6, l2 = tid&63;
  for(int jj=wv;jj<128;jj+=4){
    int j = j0+jj;
    const float* wp = Wr1 + (size_t)j*1024 + 512;
    float acc = 0.f;
#pragma unroll
    for(int q=0;q<8;q++){ int k = l2 + 64*q; acc += wp[k]*ctx[k]; }
    acc = wave_sum(acc);
    if(l2==0) ctxt[b*DFFN + j] = acc + cb1[j];
  }
}

// ---------------- fused refine (5 substeps) + finalize, one wg per batch -----------------
__global__ __launch_bounds__(256) void refine_fin(const float* __restrict__ M1,
                                                  const float* __restrict__ ctxt,
                                                  const float* __restrict__ Wr2,
                                                  const float* __restrict__ br2,
                                                  float* __restrict__ cur_x,
                                                  const float* __restrict__ W_emb,
                                                  const float* __restrict__ b_emb,
                                                  float* __restrict__ out,
                                                  float* __restrict__ h0,
                                                  unsigned short* __restrict__ h0b,
                                                  int s, int ptr){
  int b = blockIdx.x, tid = threadIdx.x;
  __shared__ float cur[DIN], gs[DFFN], dscr[DIN];
  if(tid < DIN) cur[tid] = cur_x[b*DIN + tid];
  __syncthreads();
  for(int sub=0; sub<5; sub++){
    for(int jj=tid; jj<DFFN; jj+=256){
      float u = ctxt[b*DFFN + jj];
      const float* mp = M1 + (size_t)jj*DIN;
#pragma unroll
      for(int p=0;p<8;p++){
        float4 mv = *(const float4*)(mp + 4*p);
        u += mv.x*cur[4*p] + mv.y*cur[4*p+1] + mv.z*cur[4*p+2] + mv.w*cur[4*p+3];
      }
      gs[jj] = gelu_t(u);
    }
    __syncthreads();
    int w = tid>>6, l = tid&63;
#pragma unroll
    for(int q=0;q<8;q++){
      int i = w*8 + q;
      const float* wr = Wr2 + (size_t)i*DFFN;
      float a = 0.f;
#pragma unroll
      for(int p=0;p<8;p++){
        int j0 = p*256 + l*4;
        float4 wv = *(const float4*)(wr + j0);
        float4 gv = *(const float4*)&gs[j0];
        a += wv.x*gv.x + wv.y*gv.y + wv.z*gv.z + wv.w*gv.w;
      }
      a = wave_sum(a);
      if(l==0) dscr[i] = a;
    }
    __syncthreads();
    if(tid < DIN) cur[tid] += dscr[tid] + br2[tid];
    __syncthreads();
  }
  if(tid < DIN){
    out[(b*NSTEP + s)*DIN + tid] = cur[tid];
    cur_x[b*DIN + tid] = cur[tid];
  }
  __syncthreads();
  for(int d=tid; d<DMODEL; d+=256){
    float s2 = 0.f;
#pragma unroll 8
    for(int i=0;i<DIN;i++) s2 += W_emb[d*DIN+i]*cur[i];
    float v = SCALE_EMB*(s2 + b_emb[d]) + pe_val(ptr, d);
    size_t idx = (size_t)(b*SEQ + ptr)*DMODEL + d;
    h0[idx] = v;
    h0b[idx] = f2b(v);
  }
}

// ---------------- host ----------------
extern "C" void kernel_launch(void* const* d_in, const int* in_sizes, int n_in,
                              void* d_out, int out_size, void* d_ws, size_t ws_size,
                              hipStream_t stream) {
  (void)in_sizes; (void)n_in; (void)out_size; (void)ws_size;
  const float* hist = (const float*)d_in[0];
  const float* W_emb= (const float*)d_in[2];
  const float* b_emb= (const float*)d_in[3];
  const float* Wq   = (const float*)d_in[4];
  const float* Wk   = (const float*)d_in[5];
  const float* Wv   = (const float*)d_in[6];
  const float* Wo   = (const float*)d_in[7];
  const float* ln1g = (const float*)d_in[8];
  const float* ln1b = (const float*)d_in[9];
  const float* W1   = (const float*)d_in[10];
  const float* b1   = (const float*)d_in[11];
  const float* W2   = (const float*)d_in[12];
  const float* b2v  = (const float*)d_in[13];
  const float* ln2g = (const float*)d_in[14];
  const float* ln2b = (const float*)d_in[15];
  const float* Wr1  = (const float*)d_in[16];
  const float* br1  = (const float*)d_in[17];
  const float* Wr2  = (const float*)d_in[18];
  const float* br2  = (const float*)d_in[19];
  float* out = (float*)d_out;
  float* ws  = (float*)d_ws;

  const size_t BTD = (size_t)MROWS*DMODEL;      // 262144 floats
  const size_t BTDH = BTD/2;                    // bf16 buffer in float units
  float* h0   = ws;
  unsigned short* h0b = (unsigned short*)(h0 + BTD);
  float* r2   = h0 + BTD + BTDH;
  float* hln  = r2 + BTD;
  float* hp   = hln + BTD;
  unsigned short* hpb = (unsigned short*)(hp + BTD);
  // fbuf alias block: [qb][kb][vb][attb][hlnb] = 1048576 floats
  float* qb   = hp + BTD + BTDH;
  float* kb   = qb + BTD;
  float* vb   = kb + BTD;
  unsigned short* attb = (unsigned short*)(vb + BTD);
  unsigned short* hlnb = (unsigned short*)(vb + BTD + BTDH);
  unsigned short* fbuf16 = (unsigned short*)qb;   // [512][2048] bf16
  float* r1   = qb;                                // alias (qb dead when Wo writes)
  unsigned short* W16 = (unsigned short*)(qb + 4*BTD);
  float* after_w = qb + 4*BTD + 6291456;
  float* M1   = after_w;
  float* cb1  = M1 + (size_t)DFFN*DIN;
  float* ctxt = cb1 + DFFN;
  float* cur_x= ctxt + NB*DFFN;

  unsigned short* Wq16 = W16;
  unsigned short* Wk16 = W16 + 1048576;
  unsigned short* Wv16 = W16 + 2097152;
  unsigned short* Wo16 = W16 + 3145728;
  unsigned short* W116 = W16 + 4194304;
  unsigned short* W216 = W16 + 8388608;

  conv_w<<<dim3(6144),dim3(256),0,stream>>>(Wq,Wk,Wv,Wo,W1,W2,W16);
  init_h0<<<dim3(MROWS),dim3(256),0,stream>>>(hist,W_emb,b_emb,h0,h0b);
  init_misc<<<dim3(256),dim3(256),0,stream>>>(Wr1,W_emb,b_emb,br1,hist,M1,cb1,cur_x);

  for(int s=0;s<NSTEP;s++){
    int ptr = TH_ + s;
    for(int l=0;l<4;l++){
      if(l>0)
        lnpass<<<dim3(128),dim3(256),0,stream>>>(r2, ln2g+(l-1)*DMODEL, ln2b+(l-1)*DMODEL, hln, hlnb);
      const unsigned short* A16 = (l==0)? h0b : hlnb;
      const float* res1 = (l==0)? h0 : hln;

      // fused QKV: N=1536 -> qb/kb/vb
      gemm_bf<<<dim3(12,8),dim3(256),0,stream>>>(A16, DMODEL,
          Wq16 + (size_t)l*262144, Wk16 + (size_t)l*262144, Wv16 + (size_t)l*262144,
          nullptr, nullptr, qb, nullptr, 0, 2, 0);

      attn_k<<<dim3(4,NHEAD,NB),dim3(256),0,stream>>>(qb,kb,vb,attb);

      // Wo: att@Wo^T + resid -> r1 (fp32)
      gemm_bf<<<dim3(4,8),dim3(256),0,stream>>>(attb, DMODEL,
          Wo16 + (size_t)l*262144, nullptr, nullptr,
          nullptr, res1, r1, nullptr, DMODEL, 0, 0);

      lnpass<<<dim3(128),dim3(256),0,stream>>>(r1, ln1g+l*DMODEL, ln1b+l*DMODEL, hp, hpb);

      // FF1: gelu(hp@W1^T + b1) -> fbuf bf16
      gemm_bf<<<dim3(16,8),dim3(256),0,stream>>>(hpb, DMODEL,
          W116 + (size_t)l*1048576, nullptr, nullptr,
          b1 + l*DFFN, nullptr, nullptr, fbuf16, DFFN, 1, 1);

      // FF2: fbuf@W2^T + b2 + hp -> r2 fp32
      gemm_bf<<<dim3(4,8),dim3(256),0,stream>>>(fbuf16, DFFN,
          W216 + (size_t)l*1048576, nullptr, nullptr,
          b2v + l*DMODEL, hp, r2, nullptr, DMODEL, 0, 0);
    }

    ctx_k<<<dim3(16,NB),dim3(256),0,stream>>>(r2, ln2g + 3*DMODEL, ln2b + 3*DMODEL,
                                              Wr1, cb1, ctxt, ptr);
    refine_fin<<<dim3(NB),dim3(256),0,stream>>>(M1, ctxt, Wr2, br2, cur_x,
                                                W_emb, b_emb, out, h0, h0b, s, ptr);
  }
}